// Round 4
// baseline (660.569 us; speedup 1.0000x reference)
//
#include <hip/hip_runtime.h>

#define B_SZ 32
#define LK   4096
#define H    512
#define MT   32           // key rows per block
#define NK8  64           // H/8 k-octets
#define AST  528          // LDS byte stride per k8: 32*16 + 16 pad

typedef __bf16 bf16x8 __attribute__((ext_vector_type(8)));
typedef float  f32x4  __attribute__((ext_vector_type(4)));

__device__ inline unsigned short f2bf_rne(float f) {
    unsigned int u = __float_as_uint(f);
    u += 0x7FFFu + ((u >> 16) & 1u);
    return (unsigned short)(u >> 16);
}
__device__ inline unsigned pack_trunc(float lo, float hi) {
    return __builtin_amdgcn_perm(__float_as_uint(hi), __float_as_uint(lo), 0x07060302u);
}
__device__ inline float tanh_fast(float x) {
    float e = __expf(2.0f * x);
    return 1.0f - 2.0f * __builtin_amdgcn_rcpf(e + 1.0f);
}

// ---- kernel 1: Ua_w fp32 [n][k] -> bf16 k-major tiles ua_t[k8][n][8] ----
__global__ void cvt_ua_kernel(const float* __restrict__ Ua_w, unsigned short* __restrict__ ua_t) {
    int n = blockIdx.x;          // 512 blocks
    int t = threadIdx.x;         // 256 threads, each 2 k's
    float2 f = *(const float2*)(Ua_w + n * H + t * 2);
    unsigned w = (unsigned)f2bf_rne(f.x) | ((unsigned)f2bf_rne(f.y) << 16);
    int k8 = t >> 2, off = t & 3;
    *(unsigned*)(ua_t + (size_t)k8 * (H * 8) + n * 8 + off * 2) = w;
}

// ---- kernel 2: qadd[b][n] = query[b] . Wa_w[n] + Wa_b[n] + Ua_b[n] ----
__global__ void qproj_kernel(const float* __restrict__ query, const float* __restrict__ Wa_w,
                             const float* __restrict__ Wa_b, const float* __restrict__ Ua_b,
                             float* __restrict__ qadd) {
    __shared__ float qs[H];
    int b = blockIdx.x >> 3;
    int hseg = (blockIdx.x & 7) * 64;
    int t = threadIdx.x, wave = t >> 6, lane = t & 63;
    qs[t] = query[b * H + t];
    qs[t + 256] = query[b * H + t + 256];
    __syncthreads();
    for (int i = 0; i < 16; ++i) {
        int h = hseg + wave * 16 + i;
        const float* wr = Wa_w + (size_t)h * H + lane * 8;
        float4 a = *(const float4*)wr;
        float4 c = *(const float4*)(wr + 4);
        const float* q8 = qs + lane * 8;
        float s = a.x * q8[0] + a.y * q8[1] + a.z * q8[2] + a.w * q8[3]
                + c.x * q8[4] + c.y * q8[5] + c.z * q8[6] + c.w * q8[7];
        s += __shfl_xor(s, 1);  s += __shfl_xor(s, 2);  s += __shfl_xor(s, 4);
        s += __shfl_xor(s, 8);  s += __shfl_xor(s, 16); s += __shfl_xor(s, 32);
        if (lane == 0) qadd[b * H + h] = s + Wa_b[h] + Ua_b[h];
    }
}

// ---- kernel 3: main fused kernel ----
// grid 4096 = 32 b x 128 row-tiles of 32; 256 threads (4 waves)
// n processed in 2 chunks of 256 (wave slice 64/chunk) -> acc = 32 AGPRs
__global__ __launch_bounds__(256, 4)
void main_kernel(const float* __restrict__ keys, const unsigned short* __restrict__ ua_t,
                 const float* __restrict__ qadd, const float* __restrict__ va_w,
                 const float* __restrict__ va_b, const float* __restrict__ temp,
                 const int* __restrict__ valid, float* __restrict__ p_out,
                 float* __restrict__ pc_part, float* __restrict__ psum_part) {
    __shared__ __align__(16) unsigned char alds[NK8 * AST];  // 33792 B (reused as red buf)
    __shared__ float swave[4][MT];
    __shared__ float pbuf[MT];

    const int blk  = blockIdx.x;
    const int b    = blk >> 7;
    const int m0   = (blk & 127) * MT;
    const int t    = threadIdx.x;
    const int wave = t >> 6;
    const int lane = t & 63;
    const int lrow = lane & 15;
    const int lquad = lane >> 4;

    const float* keys_b = keys + ((size_t)b * LK + m0) * H;

    // ---- stage: 32 rows x 512 k fp32 -> bf16 LDS [k8][row][8] (trunc pack) ----
    #pragma unroll
    for (int it = 0; it < 8; ++it) {
        int i = it * 256 + t;        // 0..2047
        int k8 = i & 63, row = i >> 6;
        const float* src = keys_b + row * H + k8 * 8;
        float4 f0 = *(const float4*)src;
        float4 f1 = *(const float4*)(src + 4);
        uint4 w;
        w.x = pack_trunc(f0.x, f0.y);
        w.y = pack_trunc(f0.z, f0.w);
        w.z = pack_trunc(f1.x, f1.y);
        w.w = pack_trunc(f1.z, f1.w);
        *(uint4*)(alds + k8 * AST + row * 16) = w;
    }
    __syncthreads();

    // ---- 2 n-chunks of 256; wave n-slice = ch*256 + wave*64 ----
    for (int ch = 0; ch < 2; ++ch) {
        const int nb = ch * 256 + wave * 64;

        float va[4], qa[4];
        #pragma unroll
        for (int nt = 0; nt < 4; ++nt) {
            int n = nb + nt * 16 + lrow;
            va[nt] = va_w[n];
            qa[nt] = qadd[b * H + n];
        }

        f32x4 acc[2][4];
        #pragma unroll
        for (int mt = 0; mt < 2; ++mt)
            #pragma unroll
            for (int nt = 0; nt < 4; ++nt)
                acc[mt][nt] = (f32x4){0.f, 0.f, 0.f, 0.f};

        #pragma unroll
        for (int ks = 0; ks < 16; ++ks) {
            int k8g = ks * 4 + lquad;
            bf16x8 af[2];
            #pragma unroll
            for (int mt = 0; mt < 2; ++mt)
                af[mt] = *(const bf16x8*)(alds + k8g * AST + (mt * 16 + lrow) * 16);
            #pragma unroll
            for (int nt = 0; nt < 4; ++nt) {
                bf16x8 bfrag = *(const bf16x8*)(ua_t + (size_t)k8g * (H * 8) + (nb + nt * 16 + lrow) * 8);
                #pragma unroll
                for (int mt = 0; mt < 2; ++mt)
                    acc[mt][nt] = __builtin_amdgcn_mfma_f32_16x16x32_bf16(af[mt], bfrag, acc[mt][nt], 0, 0, 0);
            }
        }

        // partial score over this n-chunk
        #pragma unroll
        for (int mt = 0; mt < 2; ++mt) {
            #pragma unroll
            for (int r = 0; r < 4; ++r) {
                float s = 0.f;
                #pragma unroll
                for (int nt = 0; nt < 4; ++nt)
                    s += tanh_fast(acc[mt][nt][r] + qa[nt]) * va[nt];
                s += __shfl_xor(s, 1); s += __shfl_xor(s, 2);
                s += __shfl_xor(s, 4); s += __shfl_xor(s, 8);
                if (lrow == 0) {
                    int row = mt * 16 + lquad * 4 + r;
                    if (ch == 0) swave[wave][row] = s;
                    else         swave[wave][row] += s;
                }
            }
        }
    }
    __syncthreads();

    // ---- p = exp(score/T) masked; per-block psum partial ----
    if (t < MT) {
        float score = (swave[0][t] + swave[1][t] + swave[2][t] + swave[3][t] + va_b[0]) / temp[0];
        int l = m0 + t;
        float p = (l < valid[b]) ? __expf(score) : 0.f;
        p_out[(size_t)b * LK + l] = p;
        pbuf[t] = p;
        float s = p;
        s += __shfl_xor(s, 1); s += __shfl_xor(s, 2); s += __shfl_xor(s, 4);
        s += __shfl_xor(s, 8); s += __shfl_xor(s, 16);
        if (t == 0) psum_part[blk] = s;
    }
    __syncthreads();

    // ---- partial context: pc_part[blk][h] = sum_row p[row]*key_bf[row][h] ----
    float s8[8];
    {
        int oct = t & 63, rg = t >> 6;     // k-octet x row-group of 8
        #pragma unroll
        for (int j = 0; j < 8; ++j) s8[j] = 0.f;
        #pragma unroll
        for (int rr = 0; rr < 8; ++rr) {
            int row = rg * 8 + rr;
            bf16x8 kv = *(const bf16x8*)(alds + oct * AST + row * 16);
            float pr = pbuf[row];
            #pragma unroll
            for (int j = 0; j < 8; ++j)
                s8[j] += pr * (float)kv[j];
        }
    }
    __syncthreads();                       // all alds reads done; safe to overlay
    {
        float* red = (float*)alds;         // red[4][512] overlays alds (8 KB)
        int oct = t & 63, rg = t >> 6;
        #pragma unroll
        for (int j = 0; j < 8; ++j)
            red[rg * H + oct * 8 + j] = s8[j];
    }
    __syncthreads();
    {
        const float* red = (const float*)alds;
        #pragma unroll
        for (int rep = 0; rep < 2; ++rep) {
            int h = t + rep * 256;
            pc_part[(size_t)blk * H + h] = red[0 * H + h] + red[1 * H + h] + red[2 * H + h] + red[3 * H + h];
        }
    }
}

// ---- kernel 4: finalize ----
// grid 32*18: seg 0..15 -> weights chunks; seg 16,17 -> context halves
__global__ void finalize_kernel(const float* __restrict__ p, const float* __restrict__ pc_part,
                                const float* __restrict__ psum_part, float* __restrict__ out) {
    int b = blockIdx.x / 18;
    int seg = blockIdx.x % 18;
    int t = threadIdx.x;
    __shared__ float tmp[2];
    if (t < 128) {
        float v = psum_part[b * 128 + t];
        v += __shfl_xor(v, 1);  v += __shfl_xor(v, 2);  v += __shfl_xor(v, 4);
        v += __shfl_xor(v, 8);  v += __shfl_xor(v, 16); v += __shfl_xor(v, 32);
        if ((t & 63) == 0) tmp[t >> 6] = v;
    }
    __syncthreads();
    float inv = 1.0f / (tmp[0] + tmp[1]);
    if (seg < 16) {
        int l = seg * 256 + t;
        out[B_SZ * H + (size_t)b * LK + l] = p[(size_t)b * LK + l] * inv;
    } else {
        int h = (seg - 16) * 256 + t;
        float s = 0.f;
        #pragma unroll 8
        for (int i = 0; i < 128; ++i)
            s += pc_part[((size_t)b * 128 + i) * H + h];
        out[b * H + h] = s * inv;
    }
}

extern "C" void kernel_launch(void* const* d_in, const int* in_sizes, int n_in,
                              void* d_out, int out_size, void* d_ws, size_t ws_size,
                              hipStream_t stream) {
    const float* query = (const float*)d_in[0];
    const float* keys  = (const float*)d_in[1];
    const float* Wa_w  = (const float*)d_in[2];
    const float* Wa_b  = (const float*)d_in[3];
    const float* Ua_w  = (const float*)d_in[4];
    const float* Ua_b  = (const float*)d_in[5];
    const float* Va_w  = (const float*)d_in[6];
    const float* Va_b  = (const float*)d_in[7];
    const float* temp  = (const float*)d_in[8];
    const int*   valid = (const int*)d_in[9];
    float* out = (float*)d_out;

    char* ws = (char*)d_ws;
    unsigned short* ua_t = (unsigned short*)ws;            //   524288 B
    float* qadd      = (float*)(ws + 524288);              //    65536 B
    float* p         = (float*)(ws + 589824);              //   524288 B
    float* psum_part = (float*)(ws + 1114112);             //    16384 B
    float* pc_part   = (float*)(ws + 1130496);             //  8388608 B

    cvt_ua_kernel<<<H, 256, 0, stream>>>(Ua_w, ua_t);
    qproj_kernel<<<B_SZ * 8, 256, 0, stream>>>(query, Wa_w, Wa_b, Ua_b, qadd);
    main_kernel<<<B_SZ * (LK / MT), 256, 0, stream>>>(keys, ua_t, qadd, Va_w, Va_b,
                                                      temp, valid, p, pc_part, psum_part);
    finalize_kernel<<<B_SZ * 18, 256, 0, stream>>>(p, pc_part, psum_part, out);
}

// Round 5
// 506.840 us; speedup vs baseline: 1.3033x; 1.3033x over previous
//
#include <hip/hip_runtime.h>

#define B_SZ 32
#define LK   4096
#define H    512
#define MT   32           // key rows per block
#define NK8  64           // H/8 k-octets
#define AST  528          // A-LDS byte stride per k8: 32*16 + 16 pad

typedef __bf16 bf16x8 __attribute__((ext_vector_type(8)));
typedef float  f32x4  __attribute__((ext_vector_type(4)));

__device__ inline unsigned short f2bf_rne(float f) {
    unsigned int u = __float_as_uint(f);
    u += 0x7FFFu + ((u >> 16) & 1u);
    return (unsigned short)(u >> 16);
}
__device__ inline unsigned pack_trunc(float lo, float hi) {
    return __builtin_amdgcn_perm(__float_as_uint(hi), __float_as_uint(lo), 0x07060302u);
}
__device__ inline float tanh_fast(float x) {
    float e = __expf(2.0f * x);
    return 1.0f - 2.0f * __builtin_amdgcn_rcpf(e + 1.0f);
}

// ---- kernel 1: Ua_w fp32 [n][k] -> bf16 k-major tiles ua_t[k8][n][8] ----
__global__ void cvt_ua_kernel(const float* __restrict__ Ua_w, unsigned short* __restrict__ ua_t) {
    int n = blockIdx.x;          // 512 blocks
    int t = threadIdx.x;         // 256 threads, each 2 k's
    float2 f = *(const float2*)(Ua_w + n * H + t * 2);
    unsigned w = (unsigned)f2bf_rne(f.x) | ((unsigned)f2bf_rne(f.y) << 16);
    int k8 = t >> 2, off = t & 3;
    *(unsigned*)(ua_t + (size_t)k8 * (H * 8) + n * 8 + off * 2) = w;
}

// ---- kernel 2: qadd[b][n] = query[b] . Wa_w[n] + Wa_b[n] + Ua_b[n] ----
__global__ void qproj_kernel(const float* __restrict__ query, const float* __restrict__ Wa_w,
                             const float* __restrict__ Wa_b, const float* __restrict__ Ua_b,
                             float* __restrict__ qadd) {
    __shared__ float qs[H];
    int b = blockIdx.x >> 3;
    int hseg = (blockIdx.x & 7) * 64;
    int t = threadIdx.x, wave = t >> 6, lane = t & 63;
    qs[t] = query[b * H + t];
    qs[t + 256] = query[b * H + t + 256];
    __syncthreads();
    for (int i = 0; i < 16; ++i) {
        int h = hseg + wave * 16 + i;
        const float* wr = Wa_w + (size_t)h * H + lane * 8;
        float4 a = *(const float4*)wr;
        float4 c = *(const float4*)(wr + 4);
        const float* q8 = qs + lane * 8;
        float s = a.x * q8[0] + a.y * q8[1] + a.z * q8[2] + a.w * q8[3]
                + c.x * q8[4] + c.y * q8[5] + c.z * q8[6] + c.w * q8[7];
        s += __shfl_xor(s, 1);  s += __shfl_xor(s, 2);  s += __shfl_xor(s, 4);
        s += __shfl_xor(s, 8);  s += __shfl_xor(s, 16); s += __shfl_xor(s, 32);
        if (lane == 0) qadd[b * H + h] = s + Wa_b[h] + Ua_b[h];
    }
}

// ---- kernel 3: main fused kernel ----
// grid 4096 = 32 b x 128 row-tiles of 32; 256 threads (4 waves)
// A (keys tile) in LDS bf16; B (ua_t) streamed through LDS via global_load_lds
// in 16 chunks of 32k x 512n (32 KB, contiguous slab). acc[2][8] = 64 AGPR.
__global__ __launch_bounds__(256, 2)
void main_kernel(const float* __restrict__ keys, const unsigned short* __restrict__ ua_t,
                 const float* __restrict__ qadd, const float* __restrict__ va_w,
                 const float* __restrict__ va_b, const float* __restrict__ temp,
                 const int* __restrict__ valid, float* __restrict__ p_out,
                 float* __restrict__ pc_part, float* __restrict__ psum_part) {
    __shared__ __align__(16) unsigned char alds[NK8 * AST];  // 33792 B
    __shared__ __align__(16) unsigned char blds[32768];      // B chunk (reused as red)
    __shared__ float swave[4][MT];
    __shared__ float pbuf[MT];

    const int blk  = blockIdx.x;
    const int b    = blk >> 7;
    const int m0   = (blk & 127) * MT;
    const int t    = threadIdx.x;
    const int wave = t >> 6;
    const int lane = t & 63;
    const int lrow = lane & 15;
    const int lquad = lane >> 4;

    const float* keys_b = keys + ((size_t)b * LK + m0) * H;

    // async B-chunk stage: 32 KB contiguous slab of ua_t -> blds (linear)
    auto issueB = [&](int kc) {
        const unsigned short* slab = ua_t + (size_t)kc * (4 * 512 * 8);
        #pragma unroll
        for (int it = 0; it < 8; ++it) {
            int i = it * 256 + t;                  // 0..2047, 16 B each
            __builtin_amdgcn_global_load_lds(
                (const __attribute__((address_space(1))) void*)(slab + (size_t)i * 8),
                (__attribute__((address_space(3))) void*)(blds + i * 16),
                16, 0, 0);
        }
    };

    issueB(0);   // overlap first B chunk with A staging

    // ---- stage A: 32 rows x 512 k fp32 -> bf16 LDS [k8][row][16B] ----
    #pragma unroll
    for (int it = 0; it < 8; ++it) {
        int i = it * 256 + t;        // 0..2047
        int k8 = i & 63, row = i >> 6;
        const float* src = keys_b + row * H + k8 * 8;
        float4 f0 = *(const float4*)src;
        float4 f1 = *(const float4*)(src + 4);
        uint4 w;
        w.x = pack_trunc(f0.x, f0.y);
        w.y = pack_trunc(f0.z, f0.w);
        w.z = pack_trunc(f1.x, f1.y);
        w.w = pack_trunc(f1.z, f1.w);
        *(uint4*)(alds + k8 * AST + row * 16) = w;
    }

    float va[8], qa[8];
    #pragma unroll
    for (int nt = 0; nt < 8; ++nt) {
        int n = wave * 128 + nt * 16 + lrow;
        va[nt] = va_w[n];
        qa[nt] = qadd[b * H + n];
    }

    f32x4 acc[2][8];
    #pragma unroll
    for (int mt = 0; mt < 2; ++mt)
        #pragma unroll
        for (int nt = 0; nt < 8; ++nt)
            acc[mt][nt] = (f32x4){0.f, 0.f, 0.f, 0.f};

    __syncthreads();   // A staged + B(0) arrived

    // ---- K-loop: 16 chunks of 32 k ----
    for (int kc = 0; kc < 16; ++kc) {
        bf16x8 af[2];
        #pragma unroll
        for (int mt = 0; mt < 2; ++mt)
            af[mt] = *(const bf16x8*)(alds + (kc * 4 + lquad) * AST + (mt * 16 + lrow) * 16);
        #pragma unroll
        for (int nt = 0; nt < 8; ++nt) {
            int n = wave * 128 + nt * 16 + lrow;
            bf16x8 bfrag = *(const bf16x8*)(blds + (lquad * 512 + n) * 16);
            acc[0][nt] = __builtin_amdgcn_mfma_f32_16x16x32_bf16(af[0], bfrag, acc[0][nt], 0, 0, 0);
            acc[1][nt] = __builtin_amdgcn_mfma_f32_16x16x32_bf16(af[1], bfrag, acc[1][nt], 0, 0, 0);
        }
        __syncthreads();                 // all waves done reading blds
        if (kc < 15) {
            issueB(kc + 1);
            __syncthreads();             // B(kc+1) arrived (vmcnt drain)
        }
    }

    // ---- score: per row, sum_n tanh(kproj + qadd) * va ----
    #pragma unroll
    for (int mt = 0; mt < 2; ++mt) {
        #pragma unroll
        for (int r = 0; r < 4; ++r) {
            float s = 0.f;
            #pragma unroll
            for (int nt = 0; nt < 8; ++nt)
                s += tanh_fast(acc[mt][nt][r] + qa[nt]) * va[nt];
            s += __shfl_xor(s, 1); s += __shfl_xor(s, 2);
            s += __shfl_xor(s, 4); s += __shfl_xor(s, 8);
            if (lrow == 0) swave[wave][mt * 16 + lquad * 4 + r] = s;
        }
    }
    __syncthreads();

    // ---- p = exp(score/T) masked; per-block psum partial ----
    if (t < MT) {
        float score = (swave[0][t] + swave[1][t] + swave[2][t] + swave[3][t] + va_b[0]) / temp[0];
        int l = m0 + t;
        float p = (l < valid[b]) ? __expf(score) : 0.f;
        p_out[(size_t)b * LK + l] = p;
        pbuf[t] = p;
        float s = p;
        s += __shfl_xor(s, 1); s += __shfl_xor(s, 2); s += __shfl_xor(s, 4);
        s += __shfl_xor(s, 8); s += __shfl_xor(s, 16);
        if (t == 0) psum_part[blk] = s;
    }
    __syncthreads();

    // ---- partial context: pc_part[blk][h] = sum_row p[row]*key_bf[row][h] ----
    {
        float* red = (float*)blds;         // overlay B buffer (8 KB used)
        int oct = t & 63, rg = t >> 6;     // k-octet x row-group of 8
        float s8[8];
        #pragma unroll
        for (int j = 0; j < 8; ++j) s8[j] = 0.f;
        #pragma unroll
        for (int rr = 0; rr < 8; ++rr) {
            int row = rg * 8 + rr;
            bf16x8 kv = *(const bf16x8*)(alds + oct * AST + row * 16);
            float pr = pbuf[row];
            #pragma unroll
            for (int j = 0; j < 8; ++j)
                s8[j] += pr * (float)kv[j];
        }
        #pragma unroll
        for (int j = 0; j < 8; ++j)
            red[rg * H + oct * 8 + j] = s8[j];
    }
    __syncthreads();
    {
        const float* red = (const float*)blds;
        #pragma unroll
        for (int rep = 0; rep < 2; ++rep) {
            int h = t + rep * 256;
            pc_part[(size_t)blk * H + h] = red[0 * H + h] + red[1 * H + h] + red[2 * H + h] + red[3 * H + h];
        }
    }
}

// ---- kernel 4: finalize ----
__global__ void finalize_kernel(const float* __restrict__ p, const float* __restrict__ pc_part,
                                const float* __restrict__ psum_part, float* __restrict__ out) {
    int b = blockIdx.x / 18;
    int seg = blockIdx.x % 18;
    int t = threadIdx.x;
    __shared__ float tmp[2];
    if (t < 128) {
        float v = psum_part[b * 128 + t];
        v += __shfl_xor(v, 1);  v += __shfl_xor(v, 2);  v += __shfl_xor(v, 4);
        v += __shfl_xor(v, 8);  v += __shfl_xor(v, 16); v += __shfl_xor(v, 32);
        if ((t & 63) == 0) tmp[t >> 6] = v;
    }
    __syncthreads();
    float inv = 1.0f / (tmp[0] + tmp[1]);
    if (seg < 16) {
        int l = seg * 256 + t;
        out[B_SZ * H + (size_t)b * LK + l] = p[(size_t)b * LK + l] * inv;
    } else {
        int h = (seg - 16) * 256 + t;
        float s = 0.f;
        #pragma unroll 8
        for (int i = 0; i < 128; ++i)
            s += pc_part[((size_t)b * 128 + i) * H + h];
        out[b * H + h] = s * inv;
    }
}

extern "C" void kernel_launch(void* const* d_in, const int* in_sizes, int n_in,
                              void* d_out, int out_size, void* d_ws, size_t ws_size,
                              hipStream_t stream) {
    const float* query = (const float*)d_in[0];
    const float* keys  = (const float*)d_in[1];
    const float* Wa_w  = (const float*)d_in[2];
    const float* Wa_b  = (const float*)d_in[3];
    const float* Ua_w  = (const float*)d_in[4];
    const float* Ua_b  = (const float*)d_in[5];
    const float* Va_w  = (const float*)d_in[6];
    const float* Va_b  = (const float*)d_in[7];
    const float* temp  = (const float*)d_in[8];
    const int*   valid = (const int*)d_in[9];
    float* out = (float*)d_out;

    char* ws = (char*)d_ws;
    unsigned short* ua_t = (unsigned short*)ws;            //   524288 B
    float* qadd      = (float*)(ws + 524288);              //    65536 B
    float* p         = (float*)(ws + 589824);              //   524288 B
    float* psum_part = (float*)(ws + 1114112);             //    16384 B
    float* pc_part   = (float*)(ws + 1130496);             //  8388608 B

    cvt_ua_kernel<<<H, 256, 0, stream>>>(Ua_w, ua_t);
    qproj_kernel<<<B_SZ * 8, 256, 0, stream>>>(query, Wa_w, Wa_b, Ua_b, qadd);
    main_kernel<<<B_SZ * (LK / MT), 256, 0, stream>>>(keys, ua_t, qadd, Va_w, Va_b,
                                                      temp, valid, p, pc_part, psum_part);
    finalize_kernel<<<B_SZ * 18, 256, 0, stream>>>(p, pc_part, psum_part, out);
}